// Round 2
// baseline (966.965 us; speedup 1.0000x reference)
//
#include <hip/hip_runtime.h>
#include <stdint.h>

#define T_TOK 8192
#define DMODEL 1024
#define FDIM 4096
#define NEXP 8
#define NROWS 16384      // T_TOK * K
#define MAXTILES 144

typedef __bf16 bf16x8 __attribute__((ext_vector_type(8)));
typedef float f32x4 __attribute__((ext_vector_type(4)));

__device__ __forceinline__ unsigned short f2bf(float f) {
  union { float f; unsigned u; } v; v.f = f;
  unsigned r = v.u + 0x7fffu + ((v.u >> 16) & 1u);
  return (unsigned short)(r >> 16);
}
__device__ __forceinline__ float bflo(unsigned u) {
  union { unsigned u; float f; } v; v.u = u << 16; return v.f;
}
__device__ __forceinline__ float bfhi(unsigned u) {
  union { unsigned u; float f; } v; v.u = u & 0xffff0000u; return v.f;
}

// ---------------- gate: logits + top2 + softmax + expert counts ----------------
__global__ __launch_bounds__(256) void gate_kernel(
    const float* __restrict__ gx, const float* __restrict__ Wg,
    const float* __restrict__ bg, int* __restrict__ sel,
    float* __restrict__ wts, int* __restrict__ counts)
{
  int t = blockIdx.x * 4 + (threadIdx.x >> 6);
  int lane = threadIdx.x & 63;
  const float* row = gx + (size_t)t * DMODEL;
  float acc[NEXP];
#pragma unroll
  for (int e = 0; e < NEXP; ++e) acc[e] = 0.f;
  for (int d = lane; d < DMODEL; d += 64) {
    float x = row[d];
    const float* wgr = Wg + (size_t)d * NEXP;
#pragma unroll
    for (int e = 0; e < NEXP; ++e) acc[e] += x * wgr[e];
  }
#pragma unroll
  for (int off = 32; off > 0; off >>= 1) {
#pragma unroll
    for (int e = 0; e < NEXP; ++e) acc[e] += __shfl_down(acc[e], off);
  }
  if (lane == 0) {
    float lg[NEXP];
#pragma unroll
    for (int e = 0; e < NEXP; ++e) lg[e] = acc[e] + bg[e];
    int i1 = 0; float v1 = lg[0];
#pragma unroll
    for (int e = 1; e < NEXP; ++e) if (lg[e] > v1) { v1 = lg[e]; i1 = e; }
    int i2 = -1; float v2 = -3.4e38f;
#pragma unroll
    for (int e = 0; e < NEXP; ++e) if (e != i1 && lg[e] > v2) { v2 = lg[e]; i2 = e; }
    float ez = __expf(v2 - v1);           // v2 <= v1
    float s = 1.f / (1.f + ez);
    sel[t*2] = i1; sel[t*2+1] = i2;
    wts[t*2] = s;  wts[t*2+1] = ez * s;
    atomicAdd(&counts[i1], 1);
    atomicAdd(&counts[i2], 1);
  }
}

// ---------------- offsets + tile table (single thread; E=8, <=135 tiles) ------
__global__ void scan_build_kernel(const int* __restrict__ counts,
                                  int* __restrict__ offsets, int* __restrict__ ntiles,
                                  int* __restrict__ tile_e, int* __restrict__ tile_r,
                                  int* __restrict__ tile_rend)
{
  if (threadIdx.x == 0 && blockIdx.x == 0) {
    int off = 0, nt = 0;
    for (int e = 0; e < NEXP; ++e) {
      offsets[e] = off;
      int c = counts[e];
      for (int r = 0; r < c; r += 128) {
        tile_e[nt] = e; tile_r[nt] = off + r; tile_rend[nt] = off + c; ++nt;
      }
      off += c;
    }
    offsets[NEXP] = off;
    *ntiles = nt;
  }
}

// ---------------- scatter: compact per-expert token / slot lists --------------
__global__ __launch_bounds__(256) void scatter_kernel(
    const int* __restrict__ sel, int* __restrict__ cursors,
    const int* __restrict__ offsets, int* __restrict__ token_list,
    int* __restrict__ slot_list)
{
  int t = blockIdx.x * 256 + threadIdx.x;
  if (t >= T_TOK) return;
#pragma unroll
  for (int k = 0; k < 2; ++k) {
    int e = sel[t*2 + k];
    int pos = atomicAdd(&cursors[e], 1);
    int r = offsets[e] + pos;
    token_list[r] = t;
    slot_list[r] = t*2 + k;
  }
}

// ---------------- f32 -> bf16 (8 elems / thread) ------------------------------
__global__ __launch_bounds__(256) void cvt_bf16_kernel(
    const float* __restrict__ in, unsigned short* __restrict__ out, int n8)
{
  int i = blockIdx.x * 256 + threadIdx.x;
  if (i >= n8) return;
  const float4* in4 = (const float4*)in;
  float4 v0 = in4[(size_t)i*2], v1 = in4[(size_t)i*2 + 1];
  union { unsigned short u[8]; uint4 q; } r;
  r.u[0]=f2bf(v0.x); r.u[1]=f2bf(v0.y); r.u[2]=f2bf(v0.z); r.u[3]=f2bf(v0.w);
  r.u[4]=f2bf(v1.x); r.u[5]=f2bf(v1.y); r.u[6]=f2bf(v1.z); r.u[7]=f2bf(v1.w);
  ((uint4*)out)[i] = r.q;
}

// ---------------- [R][C] f32 -> [C][R] bf16 transpose (per expert) ------------
// writes: each lane packs 4 consecutive R values -> ushort4 (8B coalesced)
__global__ __launch_bounds__(256) void transpose_cvt_kernel(
    const float* __restrict__ in, unsigned short* __restrict__ out, int R, int C)
{
  __shared__ float tb[64][65];
  size_t ebase = (size_t)blockIdx.z * (size_t)R * (size_t)C;
  int r0 = blockIdx.y * 64, c0 = blockIdx.x * 64;
  for (int i = threadIdx.x; i < 4096; i += 256) {
    int r = i >> 6, c = i & 63;
    tb[r][c] = in[ebase + (size_t)(r0 + r) * C + (c0 + c)];
  }
  __syncthreads();
#pragma unroll
  for (int p = 0; p < 4; ++p) {
    int item = p * 256 + threadIdx.x;      // 1024 items
    int c = item >> 4, r4 = (item & 15) * 4;
    ushort4 w;
    w.x = f2bf(tb[r4+0][c]); w.y = f2bf(tb[r4+1][c]);
    w.z = f2bf(tb[r4+2][c]); w.w = f2bf(tb[r4+3][c]);
    *(ushort4*)(out + ebase + (size_t)(c0 + c) * R + (r0 + r4)) = w;
  }
}

// ---------------- grouped GEMM1: H = gelu(X[tok] @ W1 + b1), bf16 out ---------
// A: gathered X rows [128][K=1024], B: W1T rows (F-major) [128][1024]
// LDS tiles [128 rows][64 k] bf16, granule-XOR swizzle, 16B granules.
// Epilogue: stage f32 to LDS (padded stride 132), read back coalesced bf16 x8.
__global__ __launch_bounds__(256) void gemm1_kernel(
    const unsigned short* __restrict__ Xb, const unsigned short* __restrict__ W1T,
    const float* __restrict__ b1, const int* __restrict__ token_list,
    const int* __restrict__ tile_e, const int* __restrict__ tile_r,
    const int* __restrict__ tile_rend, const int* __restrict__ ntiles,
    unsigned short* __restrict__ H)
{
  int bt = blockIdx.y;
  if (bt >= *ntiles) return;
  const int e = tile_e[bt];
  const int row0 = tile_r[bt];
  const int rend = tile_rend[bt];
  const int n0 = blockIdx.x * 128;

  const int tid = threadIdx.x;
  const int lane = tid & 63;
  const int wave = tid >> 6;

  __shared__ __align__(16) char smem[32768];
  unsigned short* sA = (unsigned short*)smem;            // 128*64 bf16 = 16KB
  unsigned short* sB = (unsigned short*)(smem + 16384);  // 16KB
  float* eps = (float*)smem;                             // epilogue: 32*132 f32

  const unsigned short* aptr[4];
  const unsigned short* bptr[4];
#pragma unroll
  for (int it = 0; it < 4; ++it) {
    int G = it * 256 + tid;
    int m = G >> 3, g = G & 7;
    int ch = g ^ (m & 7);
    int row = row0 + m; if (row > NROWS - 1) row = NROWS - 1;
    int tok = token_list[row];
    aptr[it] = Xb + (size_t)tok * DMODEL + ch * 8;
    bptr[it] = W1T + ((size_t)e * FDIM + (n0 + m)) * DMODEL + ch * 8;
  }

  f32x4 acc[4][4] = {};
  const int wr = wave >> 1, wc = wave & 1;
  const int lm = lane & 15, lk = lane >> 4, l7 = lane & 7;
  unsigned aoff[4], boff[4];
#pragma unroll
  for (int i = 0; i < 4; ++i) aoff[i] = (unsigned)(wr*64 + i*16 + lm) * 128;
#pragma unroll
  for (int j = 0; j < 4; ++j) boff[j] = (unsigned)(wc*64 + j*16 + lm) * 128;

  for (int kt = 0; kt < DMODEL / 64; ++kt) {
    const int kbase = kt * 64;
#pragma unroll
    for (int it = 0; it < 4; ++it) {
      char* la = (char*)sA + (it*256 + wave*64) * 16;
      __builtin_amdgcn_global_load_lds(
          (const __attribute__((address_space(1))) void*)(aptr[it] + kbase),
          (__attribute__((address_space(3))) void*)la, 16, 0, 0);
    }
#pragma unroll
    for (int it = 0; it < 4; ++it) {
      char* lb = (char*)sB + (it*256 + wave*64) * 16;
      __builtin_amdgcn_global_load_lds(
          (const __attribute__((address_space(1))) void*)(bptr[it] + kbase),
          (__attribute__((address_space(3))) void*)lb, 16, 0, 0);
    }
    __syncthreads();
#pragma unroll
    for (int ks = 0; ks < 2; ++ks) {
      const unsigned kx = (unsigned)((((ks*4 + lk) ^ l7)) << 4);
      bf16x8 a[4], b[4];
#pragma unroll
      for (int i = 0; i < 4; ++i) a[i] = *(const bf16x8*)((const char*)sA + aoff[i] + kx);
#pragma unroll
      for (int j = 0; j < 4; ++j) b[j] = *(const bf16x8*)((const char*)sB + boff[j] + kx);
#pragma unroll
      for (int i = 0; i < 4; ++i)
#pragma unroll
        for (int j = 0; j < 4; ++j)
          acc[i][j] = __builtin_amdgcn_mfma_f32_16x16x32_bf16(a[i], b[j], acc[i][j], 0, 0, 0);
    }
    __syncthreads();
  }

  // biases for this wave's 4 col-frags
  float bias[4];
#pragma unroll
  for (int j = 0; j < 4; ++j) bias[j] = b1[(size_t)e * FDIM + n0 + wc*64 + j*16 + lm];

  // epilogue: 4 chunks of 32 rows; gelu -> f32 LDS (stride 132) -> coalesced bf16
#pragma unroll
  for (int cg = 0; cg < 4; ++cg) {
    __syncthreads();
    if (wr == (cg >> 1)) {
      const int ip0 = (cg & 1) * 2;
#pragma unroll
      for (int ii = 0; ii < 2; ++ii) {
        const int i = ip0 + ii;
#pragma unroll
        for (int j = 0; j < 4; ++j) {
#pragma unroll
          for (int r = 0; r < 4; ++r) {
            float v = acc[i][j][r] + bias[j];
            float z2 = 1.5957691216f * (v + 0.044715f * v * v * v);
            float g = v / (1.f + __expf(-z2));
            int lrow = ii*16 + lk*4 + r;                 // 0..31
            eps[lrow * 132 + wc*64 + j*16 + lm] = g;
          }
        }
      }
    }
    __syncthreads();
#pragma unroll
    for (int u = 0; u < 2; ++u) {
      int item = u * 256 + tid;                          // 512 items: 32 rows x 16 oct
      int lrow = item >> 4, c8 = (item & 15) * 8;
      int gr = row0 + cg * 32 + lrow;
      if (gr < rend) {
        float4 v0 = *(const float4*)&eps[lrow * 132 + c8];
        float4 v1 = *(const float4*)&eps[lrow * 132 + c8 + 4];
        union { unsigned short u[8]; uint4 q; } pk;
        pk.u[0]=f2bf(v0.x); pk.u[1]=f2bf(v0.y); pk.u[2]=f2bf(v0.z); pk.u[3]=f2bf(v0.w);
        pk.u[4]=f2bf(v1.x); pk.u[5]=f2bf(v1.y); pk.u[6]=f2bf(v1.z); pk.u[7]=f2bf(v1.w);
        *(uint4*)(H + (size_t)gr * FDIM + n0 + c8) = pk.q;
      }
    }
  }
}

// ---------------- grouped GEMM2: ys[slot] = H @ W2 (bf16 scatter) -------------
__global__ __launch_bounds__(256) void gemm2_kernel(
    const unsigned short* __restrict__ H, const unsigned short* __restrict__ W2T,
    const int* __restrict__ slot_list,
    const int* __restrict__ tile_e, const int* __restrict__ tile_r,
    const int* __restrict__ tile_rend, const int* __restrict__ ntiles,
    unsigned short* __restrict__ ys)
{
  int bt = blockIdx.y;
  if (bt >= *ntiles) return;
  const int e = tile_e[bt];
  const int row0 = tile_r[bt];
  const int rend = tile_rend[bt];
  const int n0 = blockIdx.x * 128;

  const int tid = threadIdx.x;
  const int lane = tid & 63;
  const int wave = tid >> 6;

  __shared__ __align__(16) char smem[32768];
  unsigned short* sA = (unsigned short*)smem;
  unsigned short* sB = (unsigned short*)(smem + 16384);
  float* eps = (float*)smem;

  const unsigned short* aptr[4];
  const unsigned short* bptr[4];
#pragma unroll
  for (int it = 0; it < 4; ++it) {
    int G = it * 256 + tid;
    int m = G >> 3, g = G & 7;
    int ch = g ^ (m & 7);
    int row = row0 + m; if (row > NROWS - 1) row = NROWS - 1;
    aptr[it] = H + (size_t)row * FDIM + ch * 8;
    bptr[it] = W2T + ((size_t)e * DMODEL + (n0 + m)) * FDIM + ch * 8;
  }

  f32x4 acc[4][4] = {};
  const int wr = wave >> 1, wc = wave & 1;
  const int lm = lane & 15, lk = lane >> 4, l7 = lane & 7;
  unsigned aoff[4], boff[4];
#pragma unroll
  for (int i = 0; i < 4; ++i) aoff[i] = (unsigned)(wr*64 + i*16 + lm) * 128;
#pragma unroll
  for (int j = 0; j < 4; ++j) boff[j] = (unsigned)(wc*64 + j*16 + lm) * 128;

  for (int kt = 0; kt < FDIM / 64; ++kt) {
    const int kbase = kt * 64;
#pragma unroll
    for (int it = 0; it < 4; ++it) {
      char* la = (char*)sA + (it*256 + wave*64) * 16;
      __builtin_amdgcn_global_load_lds(
          (const __attribute__((address_space(1))) void*)(aptr[it] + kbase),
          (__attribute__((address_space(3))) void*)la, 16, 0, 0);
    }
#pragma unroll
    for (int it = 0; it < 4; ++it) {
      char* lb = (char*)sB + (it*256 + wave*64) * 16;
      __builtin_amdgcn_global_load_lds(
          (const __attribute__((address_space(1))) void*)(bptr[it] + kbase),
          (__attribute__((address_space(3))) void*)lb, 16, 0, 0);
    }
    __syncthreads();
#pragma unroll
    for (int ks = 0; ks < 2; ++ks) {
      const unsigned kx = (unsigned)((((ks*4 + lk) ^ l7)) << 4);
      bf16x8 a[4], b[4];
#pragma unroll
      for (int i = 0; i < 4; ++i) a[i] = *(const bf16x8*)((const char*)sA + aoff[i] + kx);
#pragma unroll
      for (int j = 0; j < 4; ++j) b[j] = *(const bf16x8*)((const char*)sB + boff[j] + kx);
#pragma unroll
      for (int i = 0; i < 4; ++i)
#pragma unroll
        for (int j = 0; j < 4; ++j)
          acc[i][j] = __builtin_amdgcn_mfma_f32_16x16x32_bf16(a[i], b[j], acc[i][j], 0, 0, 0);
    }
    __syncthreads();
  }

#pragma unroll
  for (int cg = 0; cg < 4; ++cg) {
    __syncthreads();
    if (wr == (cg >> 1)) {
      const int ip0 = (cg & 1) * 2;
#pragma unroll
      for (int ii = 0; ii < 2; ++ii) {
        const int i = ip0 + ii;
#pragma unroll
        for (int j = 0; j < 4; ++j) {
#pragma unroll
          for (int r = 0; r < 4; ++r) {
            int lrow = ii*16 + lk*4 + r;
            eps[lrow * 132 + wc*64 + j*16 + lm] = acc[i][j][r];
          }
        }
      }
    }
    __syncthreads();
#pragma unroll
    for (int u = 0; u < 2; ++u) {
      int item = u * 256 + tid;
      int lrow = item >> 4, c8 = (item & 15) * 8;
      int gr = row0 + cg * 32 + lrow;
      if (gr < rend) {
        int slot = slot_list[gr];
        float4 v0 = *(const float4*)&eps[lrow * 132 + c8];
        float4 v1 = *(const float4*)&eps[lrow * 132 + c8 + 4];
        union { unsigned short u[8]; uint4 q; } pk;
        pk.u[0]=f2bf(v0.x); pk.u[1]=f2bf(v0.y); pk.u[2]=f2bf(v0.z); pk.u[3]=f2bf(v0.w);
        pk.u[4]=f2bf(v1.x); pk.u[5]=f2bf(v1.y); pk.u[6]=f2bf(v1.z); pk.u[7]=f2bf(v1.w);
        *(uint4*)(ys + (size_t)slot * DMODEL + n0 + c8) = pk.q;
      }
    }
  }
}

// ---------------- combine: out = sum_k w_k*(y_k + b2[e_k]) --------------------
__global__ __launch_bounds__(256) void combine_kernel(
    const unsigned short* __restrict__ ys, const float* __restrict__ wts,
    const int* __restrict__ sel, const float* __restrict__ b2,
    float* __restrict__ out)
{
  int i = blockIdx.x * 256 + threadIdx.x;   // over T*D/8
  int t = i >> 7, d8 = i & 127;
  float w0 = wts[t*2], w1 = wts[t*2 + 1];
  int e0 = sel[t*2], e1 = sel[t*2 + 1];
  const uint4* ys4 = (const uint4*)ys;
  uint4 ya = ys4[(size_t)(t*2) * 128 + d8];
  uint4 yb = ys4[(size_t)(t*2 + 1) * 128 + d8];
  const float4* b24 = (const float4*)b2;
  float4 c0a = b24[e0*256 + d8*2], c0b = b24[e0*256 + d8*2 + 1];
  float4 c1a = b24[e1*256 + d8*2], c1b = b24[e1*256 + d8*2 + 1];
  float4 o0, o1;
  o0.x = w0*(bflo(ya.x)+c0a.x) + w1*(bflo(yb.x)+c1a.x);
  o0.y = w0*(bfhi(ya.x)+c0a.y) + w1*(bfhi(yb.x)+c1a.y);
  o0.z = w0*(bflo(ya.y)+c0a.z) + w1*(bflo(yb.y)+c1a.z);
  o0.w = w0*(bfhi(ya.y)+c0a.w) + w1*(bfhi(yb.y)+c1a.w);
  o1.x = w0*(bflo(ya.z)+c0b.x) + w1*(bflo(yb.z)+c1b.x);
  o1.y = w0*(bfhi(ya.z)+c0b.y) + w1*(bfhi(yb.z)+c1b.y);
  o1.z = w0*(bflo(ya.w)+c0b.z) + w1*(bflo(yb.w)+c1b.z);
  o1.w = w0*(bfhi(ya.w)+c0b.w) + w1*(bfhi(yb.w)+c1b.w);
  float4* out4 = (float4*)out;
  out4[(size_t)t * 256 + d8*2]     = o0;
  out4[(size_t)t * 256 + d8*2 + 1] = o1;
}

// ---------------- host ---------------------------------------------------------
extern "C" void kernel_launch(void* const* d_in, const int* in_sizes, int n_in,
                              void* d_out, int out_size, void* d_ws, size_t ws_size,
                              hipStream_t stream)
{
  const float* gate_inputs = (const float*)d_in[0];
  const float* inputs      = (const float*)d_in[1];
  const float* Wg          = (const float*)d_in[2];
  const float* bg          = (const float*)d_in[3];
  const float* w1          = (const float*)d_in[4];
  const float* b1          = (const float*)d_in[5];
  const float* w2          = (const float*)d_in[6];
  const float* b2          = (const float*)d_in[7];
  float* out = (float*)d_out;

  char* ws = (char*)d_ws;
  size_t o = 0;
  auto carve = [&](size_t bytes) { void* p = ws + o; o += (bytes + 255) & ~(size_t)255; return p; };
  unsigned short* Xb  = (unsigned short*)carve((size_t)T_TOK * DMODEL * 2);
  unsigned short* W1T = (unsigned short*)carve((size_t)NEXP * FDIM * DMODEL * 2);
  unsigned short* W2T = (unsigned short*)carve((size_t)NEXP * DMODEL * FDIM * 2);
  unsigned short* H   = (unsigned short*)carve((size_t)NROWS * FDIM * 2);
  unsigned short* ys  = (unsigned short*)carve((size_t)NROWS * DMODEL * 2);
  int*   sel          = (int*)carve((size_t)NROWS * 4);
  float* wts          = (float*)carve((size_t)NROWS * 4);
  int*   token_list   = (int*)carve((size_t)(NROWS + 256) * 4);
  int*   slot_list    = (int*)carve((size_t)(NROWS + 256) * 4);
  int*   ctrl         = (int*)carve(4096);
  int* counts  = ctrl;            // 8
  int* cursors = ctrl + 8;        // 8
  int* offsets = ctrl + 16;       // 9
  int* ntiles  = ctrl + 28;       // 1
  int* tile_e  = ctrl + 32;
  int* tile_r  = ctrl + 32 + MAXTILES;
  int* tile_rend = ctrl + 32 + 2 * MAXTILES;

  hipMemsetAsync(counts, 0, 64, stream);  // counts + cursors

  gate_kernel<<<T_TOK / 4, 256, 0, stream>>>(gate_inputs, Wg, bg, sel, wts, counts);
  scan_build_kernel<<<1, 64, 0, stream>>>(counts, offsets, ntiles, tile_e, tile_r, tile_rend);
  scatter_kernel<<<T_TOK / 256, 256, 0, stream>>>(sel, cursors, offsets, token_list, slot_list);
  cvt_bf16_kernel<<<(T_TOK * DMODEL / 8) / 256, 256, 0, stream>>>(inputs, Xb, T_TOK * DMODEL / 8);
  transpose_cvt_kernel<<<dim3(FDIM / 64, DMODEL / 64, NEXP), 256, 0, stream>>>(w1, W1T, DMODEL, FDIM);
  transpose_cvt_kernel<<<dim3(DMODEL / 64, FDIM / 64, NEXP), 256, 0, stream>>>(w2, W2T, FDIM, DMODEL);
  gemm1_kernel<<<dim3(FDIM / 128, MAXTILES), 256, 0, stream>>>(Xb, W1T, b1, token_list,
      tile_e, tile_r, tile_rend, ntiles, H);
  gemm2_kernel<<<dim3(DMODEL / 128, MAXTILES), 256, 0, stream>>>(H, W2T, slot_list,
      tile_e, tile_r, tile_rend, ntiles, ys);
  combine_kernel<<<(T_TOK * DMODEL / 8) / 256, 256, 0, stream>>>(ys, wts, sel, b2, out);
}

// Round 3
// 797.944 us; speedup vs baseline: 1.2118x; 1.2118x over previous
//
#include <hip/hip_runtime.h>
#include <stdint.h>

#define T_TOK 8192
#define DMODEL 1024
#define FDIM 4096
#define NEXP 8
#define NROWS 16384      // T_TOK * K
#define MAXTILES 144
#define NB1 32           // gemm1 N-blocks (FDIM/128)
#define NB2 8            // gemm2 N-blocks (DMODEL/128)
#define NKT1 (DMODEL/64) // 16
#define NKT2 (FDIM/64)   // 64

typedef __bf16 bf16x8 __attribute__((ext_vector_type(8)));
typedef float f32x4 __attribute__((ext_vector_type(4)));

__device__ __forceinline__ unsigned short f2bf(float f) {
  union { float f; unsigned u; } v; v.f = f;
  unsigned r = v.u + 0x7fffu + ((v.u >> 16) & 1u);
  return (unsigned short)(r >> 16);
}
__device__ __forceinline__ float bflo(unsigned u) {
  union { unsigned u; float f; } v; v.u = u << 16; return v.f;
}
__device__ __forceinline__ float bfhi(unsigned u) {
  union { unsigned u; float f; } v; v.u = u & 0xffff0000u; return v.f;
}

// ---------------- gate: logits + top2 + softmax + expert counts ----------------
__global__ __launch_bounds__(256) void gate_kernel(
    const float* __restrict__ gx, const float* __restrict__ Wg,
    const float* __restrict__ bg, int* __restrict__ sel,
    float* __restrict__ wts, int* __restrict__ counts)
{
  int t = blockIdx.x * 4 + (threadIdx.x >> 6);
  int lane = threadIdx.x & 63;
  const float* row = gx + (size_t)t * DMODEL;
  float acc[NEXP];
#pragma unroll
  for (int e = 0; e < NEXP; ++e) acc[e] = 0.f;
  for (int d = lane; d < DMODEL; d += 64) {
    float x = row[d];
    const float* wgr = Wg + (size_t)d * NEXP;
#pragma unroll
    for (int e = 0; e < NEXP; ++e) acc[e] += x * wgr[e];
  }
#pragma unroll
  for (int off = 32; off > 0; off >>= 1) {
#pragma unroll
    for (int e = 0; e < NEXP; ++e) acc[e] += __shfl_down(acc[e], off);
  }
  if (lane == 0) {
    float lg[NEXP];
#pragma unroll
    for (int e = 0; e < NEXP; ++e) lg[e] = acc[e] + bg[e];
    int i1 = 0; float v1 = lg[0];
#pragma unroll
    for (int e = 1; e < NEXP; ++e) if (lg[e] > v1) { v1 = lg[e]; i1 = e; }
    int i2 = -1; float v2 = -3.4e38f;
#pragma unroll
    for (int e = 0; e < NEXP; ++e) if (e != i1 && lg[e] > v2) { v2 = lg[e]; i2 = e; }
    float ez = __expf(v2 - v1);           // v2 <= v1
    float s = 1.f / (1.f + ez);
    sel[t*2] = i1; sel[t*2+1] = i2;
    wts[t*2] = s;  wts[t*2+1] = ez * s;
    atomicAdd(&counts[i1], 1);
    atomicAdd(&counts[i2], 1);
  }
}

// ---------------- offsets + tile table (single thread; E=8, <=135 tiles) ------
__global__ void scan_build_kernel(const int* __restrict__ counts,
                                  int* __restrict__ offsets, int* __restrict__ ntiles,
                                  int* __restrict__ tile_e, int* __restrict__ tile_r,
                                  int* __restrict__ tile_rend)
{
  if (threadIdx.x == 0 && blockIdx.x == 0) {
    int off = 0, nt = 0;
    for (int e = 0; e < NEXP; ++e) {
      offsets[e] = off;
      int c = counts[e];
      for (int r = 0; r < c; r += 128) {
        tile_e[nt] = e; tile_r[nt] = off + r; tile_rend[nt] = off + c; ++nt;
      }
      off += c;
    }
    offsets[NEXP] = off;
    *ntiles = nt;
  }
}

// ---------------- scatter: compact per-expert token / slot lists --------------
__global__ __launch_bounds__(256) void scatter_kernel(
    const int* __restrict__ sel, int* __restrict__ cursors,
    const int* __restrict__ offsets, int* __restrict__ token_list,
    int* __restrict__ slot_list)
{
  int t = blockIdx.x * 256 + threadIdx.x;
  if (t >= T_TOK) return;
#pragma unroll
  for (int k = 0; k < 2; ++k) {
    int e = sel[t*2 + k];
    int pos = atomicAdd(&cursors[e], 1);
    int r = offsets[e] + pos;
    token_list[r] = t;
    slot_list[r] = t*2 + k;
  }
}

// ---------------- f32 -> bf16 (8 elems / thread) ------------------------------
__global__ __launch_bounds__(256) void cvt_bf16_kernel(
    const float* __restrict__ in, unsigned short* __restrict__ out, int n8)
{
  int i = blockIdx.x * 256 + threadIdx.x;
  if (i >= n8) return;
  const float4* in4 = (const float4*)in;
  float4 v0 = in4[(size_t)i*2], v1 = in4[(size_t)i*2 + 1];
  union { unsigned short u[8]; uint4 q; } r;
  r.u[0]=f2bf(v0.x); r.u[1]=f2bf(v0.y); r.u[2]=f2bf(v0.z); r.u[3]=f2bf(v0.w);
  r.u[4]=f2bf(v1.x); r.u[5]=f2bf(v1.y); r.u[6]=f2bf(v1.z); r.u[7]=f2bf(v1.w);
  ((uint4*)out)[i] = r.q;
}

// ---------------- [R][C] f32 -> [C][R] bf16 transpose (per expert) ------------
// float4 reads (16B/lane), ushort4 writes (8B/lane)
__global__ __launch_bounds__(256) void transpose_cvt_kernel(
    const float* __restrict__ in, unsigned short* __restrict__ out, int R, int C)
{
  __shared__ float tb[64][65];
  size_t ebase = (size_t)blockIdx.z * (size_t)R * (size_t)C;
  int r0 = blockIdx.y * 64, c0 = blockIdx.x * 64;
#pragma unroll
  for (int p = 0; p < 4; ++p) {
    int item = p * 256 + threadIdx.x;     // 1024 float4 items
    int r = item >> 4, c4 = (item & 15) * 4;
    float4 v = *(const float4*)&in[ebase + (size_t)(r0 + r) * C + (c0 + c4)];
    tb[r][c4+0] = v.x; tb[r][c4+1] = v.y; tb[r][c4+2] = v.z; tb[r][c4+3] = v.w;
  }
  __syncthreads();
#pragma unroll
  for (int p = 0; p < 4; ++p) {
    int item = p * 256 + threadIdx.x;      // 1024 items
    int c = item >> 4, r4 = (item & 15) * 4;
    ushort4 w;
    w.x = f2bf(tb[r4+0][c]); w.y = f2bf(tb[r4+1][c]);
    w.z = f2bf(tb[r4+2][c]); w.w = f2bf(tb[r4+3][c]);
    *(ushort4*)(out + ebase + (size_t)(c0 + c) * R + (r0 + r4)) = w;
  }
}

// ---------------- grouped GEMM1: H = gelu(X[tok] @ W1 + b1), bf16 out ---------
// 2-phase double-buffered pipeline: stage(kt+1) issued before compute(kt),
// counted vmcnt(8) + raw s_barrier (no vmcnt(0) drain in main loop).
// LDS: [A0 16K][B0 16K][A1 16K][B1 16K] = 64 KB. granule-XOR swizzle.
__global__ __launch_bounds__(256) void gemm1_kernel(
    const unsigned short* __restrict__ Xb, const unsigned short* __restrict__ W1T,
    const float* __restrict__ b1, const int* __restrict__ token_list,
    const int* __restrict__ tile_e, const int* __restrict__ tile_r,
    const int* __restrict__ tile_rend, const int* __restrict__ ntiles,
    unsigned short* __restrict__ H)
{
  // XCD-chunked bijective swizzle (nwg = NB1*MAXTILES, %8==0)
  const int nwg = NB1 * MAXTILES;
  int bid = blockIdx.x;
  int wg = (bid & 7) * (nwg >> 3) + (bid >> 3);
  int bt = wg >> 5;                 // / NB1
  int nb = wg & (NB1 - 1);
  if (bt >= *ntiles) return;
  const int e = tile_e[bt];
  const int row0 = tile_r[bt];
  const int rend = tile_rend[bt];
  const int n0 = nb * 128;

  const int tid = threadIdx.x;
  const int lane = tid & 63;
  const int wave = tid >> 6;

  __shared__ __align__(16) char smem[65536];
  float* eps = (float*)smem;        // epilogue reuse

  const unsigned short* aptr[4];
  const unsigned short* bptr[4];
#pragma unroll
  for (int it = 0; it < 4; ++it) {
    int G = it * 256 + tid;
    int m = G >> 3, g = G & 7;
    int ch = g ^ (m & 7);
    int row = row0 + m; if (row > NROWS - 1) row = NROWS - 1;
    int tok = token_list[row];
    aptr[it] = Xb + (size_t)tok * DMODEL + ch * 8;
    bptr[it] = W1T + ((size_t)e * FDIM + (n0 + m)) * DMODEL + ch * 8;
  }

  // stage k-tile kt into buffer sel (8 x global_load_lds, 16B each)
  auto stage = [&](int kt, int sel) {
    const int kbase = kt * 64;
    char* base = smem + sel * 32768;
#pragma unroll
    for (int it = 0; it < 4; ++it) {
      __builtin_amdgcn_global_load_lds(
          (const __attribute__((address_space(1))) void*)(aptr[it] + kbase),
          (__attribute__((address_space(3))) void*)(base + it*4096 + wave*1024), 16, 0, 0);
    }
#pragma unroll
    for (int it = 0; it < 4; ++it) {
      __builtin_amdgcn_global_load_lds(
          (const __attribute__((address_space(1))) void*)(bptr[it] + kbase),
          (__attribute__((address_space(3))) void*)(base + 16384 + it*4096 + wave*1024), 16, 0, 0);
    }
  };

  f32x4 acc[4][4] = {};
  const int wr = wave >> 1, wc = wave & 1;
  const int lm = lane & 15, lk = lane >> 4, l7 = lane & 7;
  unsigned aoff[4], boff[4];
#pragma unroll
  for (int i = 0; i < 4; ++i) aoff[i] = (unsigned)(wr*64 + i*16 + lm) * 128;
#pragma unroll
  for (int j = 0; j < 4; ++j) boff[j] = (unsigned)(wc*64 + j*16 + lm) * 128;

  stage(0, 0);                                  // prologue prefetch

  for (int kt = 0; kt < NKT1; ++kt) {
    const int sel = kt & 1;
    if (kt + 1 < NKT1) {
      stage(kt + 1, sel ^ 1);                   // prefetch next tile
      asm volatile("s_waitcnt vmcnt(8)" ::: "memory");   // cur's 8 done, next in flight
    } else {
      asm volatile("s_waitcnt vmcnt(0)" ::: "memory");
    }
    __builtin_amdgcn_s_barrier();
    __builtin_amdgcn_sched_barrier(0);
    const char* base = smem + sel * 32768;
#pragma unroll
    for (int ks = 0; ks < 2; ++ks) {
      const unsigned kx = (unsigned)((((ks*4 + lk) ^ l7)) << 4);
      bf16x8 a[4], b[4];
#pragma unroll
      for (int i = 0; i < 4; ++i) a[i] = *(const bf16x8*)(base + aoff[i] + kx);
#pragma unroll
      for (int j = 0; j < 4; ++j) b[j] = *(const bf16x8*)(base + 16384 + boff[j] + kx);
#pragma unroll
      for (int i = 0; i < 4; ++i)
#pragma unroll
        for (int j = 0; j < 4; ++j)
          acc[i][j] = __builtin_amdgcn_mfma_f32_16x16x32_bf16(a[i], b[j], acc[i][j], 0, 0, 0);
    }
    __builtin_amdgcn_s_barrier();               // all reads of buf[sel] done
    __builtin_amdgcn_sched_barrier(0);
  }

  float bias[4];
#pragma unroll
  for (int j = 0; j < 4; ++j) bias[j] = b1[(size_t)e * FDIM + n0 + wc*64 + j*16 + lm];

  // epilogue: 4 chunks of 32 rows; gelu -> f32 LDS (stride 132) -> coalesced bf16
#pragma unroll
  for (int cg = 0; cg < 4; ++cg) {
    __syncthreads();
    if (wr == (cg >> 1)) {
      const int ip0 = (cg & 1) * 2;
#pragma unroll
      for (int ii = 0; ii < 2; ++ii) {
        const int i = ip0 + ii;
#pragma unroll
        for (int j = 0; j < 4; ++j) {
#pragma unroll
          for (int r = 0; r < 4; ++r) {
            float v = acc[i][j][r] + bias[j];
            float z2 = 1.5957691216f * (v + 0.044715f * v * v * v);
            float g = v / (1.f + __expf(-z2));
            int lrow = ii*16 + lk*4 + r;
            eps[lrow * 132 + wc*64 + j*16 + lm] = g;
          }
        }
      }
    }
    __syncthreads();
#pragma unroll
    for (int u = 0; u < 2; ++u) {
      int item = u * 256 + tid;
      int lrow = item >> 4, c8 = (item & 15) * 8;
      int gr = row0 + cg * 32 + lrow;
      if (gr < rend) {
        float4 v0 = *(const float4*)&eps[lrow * 132 + c8];
        float4 v1 = *(const float4*)&eps[lrow * 132 + c8 + 4];
        union { unsigned short u[8]; uint4 q; } pk;
        pk.u[0]=f2bf(v0.x); pk.u[1]=f2bf(v0.y); pk.u[2]=f2bf(v0.z); pk.u[3]=f2bf(v0.w);
        pk.u[4]=f2bf(v1.x); pk.u[5]=f2bf(v1.y); pk.u[6]=f2bf(v1.z); pk.u[7]=f2bf(v1.w);
        *(uint4*)(H + (size_t)gr * FDIM + n0 + c8) = pk.q;
      }
    }
  }
}

// ---------------- grouped GEMM2: ys[slot] = H @ W2 (bf16 scatter) -------------
__global__ __launch_bounds__(256) void gemm2_kernel(
    const unsigned short* __restrict__ H, const unsigned short* __restrict__ W2T,
    const int* __restrict__ slot_list,
    const int* __restrict__ tile_e, const int* __restrict__ tile_r,
    const int* __restrict__ tile_rend, const int* __restrict__ ntiles,
    unsigned short* __restrict__ ys)
{
  const int nwg = NB2 * MAXTILES;
  int bid = blockIdx.x;
  int wg = (bid & 7) * (nwg >> 3) + (bid >> 3);
  int bt = wg >> 3;                 // / NB2
  int nb = wg & (NB2 - 1);
  if (bt >= *ntiles) return;
  const int e = tile_e[bt];
  const int row0 = tile_r[bt];
  const int rend = tile_rend[bt];
  const int n0 = nb * 128;

  const int tid = threadIdx.x;
  const int lane = tid & 63;
  const int wave = tid >> 6;

  __shared__ __align__(16) char smem[65536];
  float* eps = (float*)smem;

  const unsigned short* aptr[4];
  const unsigned short* bptr[4];
#pragma unroll
  for (int it = 0; it < 4; ++it) {
    int G = it * 256 + tid;
    int m = G >> 3, g = G & 7;
    int ch = g ^ (m & 7);
    int row = row0 + m; if (row > NROWS - 1) row = NROWS - 1;
    aptr[it] = H + (size_t)row * FDIM + ch * 8;
    bptr[it] = W2T + ((size_t)e * DMODEL + (n0 + m)) * FDIM + ch * 8;
  }

  auto stage = [&](int kt, int sel) {
    const int kbase = kt * 64;
    char* base = smem + sel * 32768;
#pragma unroll
    for (int it = 0; it < 4; ++it) {
      __builtin_amdgcn_global_load_lds(
          (const __attribute__((address_space(1))) void*)(aptr[it] + kbase),
          (__attribute__((address_space(3))) void*)(base + it*4096 + wave*1024), 16, 0, 0);
    }
#pragma unroll
    for (int it = 0; it < 4; ++it) {
      __builtin_amdgcn_global_load_lds(
          (const __attribute__((address_space(1))) void*)(bptr[it] + kbase),
          (__attribute__((address_space(3))) void*)(base + 16384 + it*4096 + wave*1024), 16, 0, 0);
    }
  };

  f32x4 acc[4][4] = {};
  const int wr = wave >> 1, wc = wave & 1;
  const int lm = lane & 15, lk = lane >> 4, l7 = lane & 7;
  unsigned aoff[4], boff[4];
#pragma unroll
  for (int i = 0; i < 4; ++i) aoff[i] = (unsigned)(wr*64 + i*16 + lm) * 128;
#pragma unroll
  for (int j = 0; j < 4; ++j) boff[j] = (unsigned)(wc*64 + j*16 + lm) * 128;

  stage(0, 0);

  for (int kt = 0; kt < NKT2; ++kt) {
    const int sel = kt & 1;
    if (kt + 1 < NKT2) {
      stage(kt + 1, sel ^ 1);
      asm volatile("s_waitcnt vmcnt(8)" ::: "memory");
    } else {
      asm volatile("s_waitcnt vmcnt(0)" ::: "memory");
    }
    __builtin_amdgcn_s_barrier();
    __builtin_amdgcn_sched_barrier(0);
    const char* base = smem + sel * 32768;
#pragma unroll
    for (int ks = 0; ks < 2; ++ks) {
      const unsigned kx = (unsigned)((((ks*4 + lk) ^ l7)) << 4);
      bf16x8 a[4], b[4];
#pragma unroll
      for (int i = 0; i < 4; ++i) a[i] = *(const bf16x8*)(base + aoff[i] + kx);
#pragma unroll
      for (int j = 0; j < 4; ++j) b[j] = *(const bf16x8*)(base + 16384 + boff[j] + kx);
#pragma unroll
      for (int i = 0; i < 4; ++i)
#pragma unroll
        for (int j = 0; j < 4; ++j)
          acc[i][j] = __builtin_amdgcn_mfma_f32_16x16x32_bf16(a[i], b[j], acc[i][j], 0, 0, 0);
    }
    __builtin_amdgcn_s_barrier();
    __builtin_amdgcn_sched_barrier(0);
  }

#pragma unroll
  for (int cg = 0; cg < 4; ++cg) {
    __syncthreads();
    if (wr == (cg >> 1)) {
      const int ip0 = (cg & 1) * 2;
#pragma unroll
      for (int ii = 0; ii < 2; ++ii) {
        const int i = ip0 + ii;
#pragma unroll
        for (int j = 0; j < 4; ++j) {
#pragma unroll
          for (int r = 0; r < 4; ++r) {
            int lrow = ii*16 + lk*4 + r;
            eps[lrow * 132 + wc*64 + j*16 + lm] = acc[i][j][r];
          }
        }
      }
    }
    __syncthreads();
#pragma unroll
    for (int u = 0; u < 2; ++u) {
      int item = u * 256 + tid;
      int lrow = item >> 4, c8 = (item & 15) * 8;
      int gr = row0 + cg * 32 + lrow;
      if (gr < rend) {
        int slot = slot_list[gr];
        float4 v0 = *(const float4*)&eps[lrow * 132 + c8];
        float4 v1 = *(const float4*)&eps[lrow * 132 + c8 + 4];
        union { unsigned short u[8]; uint4 q; } pk;
        pk.u[0]=f2bf(v0.x); pk.u[1]=f2bf(v0.y); pk.u[2]=f2bf(v0.z); pk.u[3]=f2bf(v0.w);
        pk.u[4]=f2bf(v1.x); pk.u[5]=f2bf(v1.y); pk.u[6]=f2bf(v1.z); pk.u[7]=f2bf(v1.w);
        *(uint4*)(ys + (size_t)slot * DMODEL + n0 + c8) = pk.q;
      }
    }
  }
}

// ---------------- combine: out = sum_k w_k*(y_k + b2[e_k]) --------------------
__global__ __launch_bounds__(256) void combine_kernel(
    const unsigned short* __restrict__ ys, const float* __restrict__ wts,
    const int* __restrict__ sel, const float* __restrict__ b2,
    float* __restrict__ out)
{
  int i = blockIdx.x * 256 + threadIdx.x;   // over T*D/8
  int t = i >> 7, d8 = i & 127;
  float w0 = wts[t*2], w1 = wts[t*2 + 1];
  int e0 = sel[t*2], e1 = sel[t*2 + 1];
  const uint4* ys4 = (const uint4*)ys;
  uint4 ya = ys4[(size_t)(t*2) * 128 + d8];
  uint4 yb = ys4[(size_t)(t*2 + 1) * 128 + d8];
  const float4* b24 = (const float4*)b2;
  float4 c0a = b24[e0*256 + d8*2], c0b = b24[e0*256 + d8*2 + 1];
  float4 c1a = b24[e1*256 + d8*2], c1b = b24[e1*256 + d8*2 + 1];
  float4 o0, o1;
  o0.x = w0*(bflo(ya.x)+c0a.x) + w1*(bflo(yb.x)+c1a.x);
  o0.y = w0*(bfhi(ya.x)+c0a.y) + w1*(bfhi(yb.x)+c1a.y);
  o0.z = w0*(bflo(ya.y)+c0a.z) + w1*(bflo(yb.y)+c1a.z);
  o0.w = w0*(bfhi(ya.y)+c0a.w) + w1*(bfhi(yb.y)+c1a.w);
  o1.x = w0*(bflo(ya.z)+c0b.x) + w1*(bflo(yb.z)+c1b.x);
  o1.y = w0*(bfhi(ya.z)+c0b.y) + w1*(bfhi(yb.z)+c1b.y);
  o1.z = w0*(bflo(ya.w)+c0b.z) + w1*(bflo(yb.w)+c1b.z);
  o1.w = w0*(bfhi(ya.w)+c0b.w) + w1*(bfhi(yb.w)+c1b.w);
  float4* out4 = (float4*)out;
  out4[(size_t)t * 256 + d8*2]     = o0;
  out4[(size_t)t * 256 + d8*2 + 1] = o1;
}

// ---------------- host ---------------------------------------------------------
extern "C" void kernel_launch(void* const* d_in, const int* in_sizes, int n_in,
                              void* d_out, int out_size, void* d_ws, size_t ws_size,
                              hipStream_t stream)
{
  const float* gate_inputs = (const float*)d_in[0];
  const float* inputs      = (const float*)d_in[1];
  const float* Wg          = (const float*)d_in[2];
  const float* bg          = (const float*)d_in[3];
  const float* w1          = (const float*)d_in[4];
  const float* b1          = (const float*)d_in[5];
  const float* w2          = (const float*)d_in[6];
  const float* b2          = (const float*)d_in[7];
  float* out = (float*)d_out;

  char* ws = (char*)d_ws;
  size_t o = 0;
  auto carve = [&](size_t bytes) { void* p = ws + o; o += (bytes + 255) & ~(size_t)255; return p; };
  unsigned short* Xb  = (unsigned short*)carve((size_t)T_TOK * DMODEL * 2);
  unsigned short* W1T = (unsigned short*)carve((size_t)NEXP * FDIM * DMODEL * 2);
  unsigned short* W2T = (unsigned short*)carve((size_t)NEXP * DMODEL * FDIM * 2);
  unsigned short* H   = (unsigned short*)carve((size_t)NROWS * FDIM * 2);
  unsigned short* ys  = (unsigned short*)carve((size_t)NROWS * DMODEL * 2);
  int*   sel          = (int*)carve((size_t)NROWS * 4);
  float* wts          = (float*)carve((size_t)NROWS * 4);
  int*   token_list   = (int*)carve((size_t)(NROWS + 256) * 4);
  int*   slot_list    = (int*)carve((size_t)(NROWS + 256) * 4);
  int*   ctrl         = (int*)carve(4096);
  int* counts  = ctrl;            // 8
  int* cursors = ctrl + 8;        // 8
  int* offsets = ctrl + 16;       // 9
  int* ntiles  = ctrl + 28;       // 1
  int* tile_e  = ctrl + 32;
  int* tile_r  = ctrl + 32 + MAXTILES;
  int* tile_rend = ctrl + 32 + 2 * MAXTILES;

  hipMemsetAsync(counts, 0, 64, stream);  // counts + cursors

  gate_kernel<<<T_TOK / 4, 256, 0, stream>>>(gate_inputs, Wg, bg, sel, wts, counts);
  scan_build_kernel<<<1, 64, 0, stream>>>(counts, offsets, ntiles, tile_e, tile_r, tile_rend);
  scatter_kernel<<<T_TOK / 256, 256, 0, stream>>>(sel, cursors, offsets, token_list, slot_list);
  cvt_bf16_kernel<<<(T_TOK * DMODEL / 8) / 256, 256, 0, stream>>>(inputs, Xb, T_TOK * DMODEL / 8);
  transpose_cvt_kernel<<<dim3(FDIM / 64, DMODEL / 64, NEXP), 256, 0, stream>>>(w1, W1T, DMODEL, FDIM);
  transpose_cvt_kernel<<<dim3(DMODEL / 64, FDIM / 64, NEXP), 256, 0, stream>>>(w2, W2T, FDIM, DMODEL);
  gemm1_kernel<<<NB1 * MAXTILES, 256, 0, stream>>>(Xb, W1T, b1, token_list,
      tile_e, tile_r, tile_rend, ntiles, H);
  gemm2_kernel<<<NB2 * MAXTILES, 256, 0, stream>>>(H, W2T, slot_list,
      tile_e, tile_r, tile_rend, ntiles, ys);
  combine_kernel<<<(T_TOK * DMODEL / 8) / 256, 256, 0, stream>>>(ys, wts, sel, b2, out);
}